// Round 1
// 274.361 us; speedup vs baseline: 1.0148x; 1.0148x over previous
//
#include <hip/hip_runtime.h>
#include <hip/hip_bf16.h>

// Problem constants
#define BATCH 16
#define IN_C 3
#define Q_C 8
#define V_C 16
#define HH 224
#define WW 224
#define KK 7

// Padded layouts
#define XPH 230   // stored row = orig row + 3
#define XPW 232   // stored col = orig col + 3
#define QPH 118
#define QPW 120

// Region sizes (elements)
#define XPAD_N   (BATCH*IN_C*XPH*XPW)          // 2,561,280 f32
#define PLANES_N (BATCH*7*IN_C*XPH*QPW)        // 9,273,600 bf16
#define ONES_N   27712                          // bf16 ones (still written by kX; kC no longer reads it)
#define VPAD_N   (BATCH*V_C*QPH*QPW)           // 3,624,960 f32
#define QPADS_STRIDE (Q_C*4*QPH*QPW)           // 453,120 per (b,ic)
#define QPADS_N  (BATCH*IN_C*QPADS_STRIDE)     // 21,749,760 bf16
#define D_N      (BATCH*IN_C*128*160)          // 983,040 elements (layout: [bi][n=160][m=128])
#define SPLITS   14
#define DPART_N  (SPLITS*D_N)                  // bf16 partials
#define A_N      (BATCH*IN_C*V_C*16)
#define OUT_N    (BATCH*IN_C*58*58)
#define ONES_OFF PLANES_N

typedef __attribute__((ext_vector_type(8))) short bf16x8;
typedef __attribute__((ext_vector_type(4))) float f32x4;
typedef __attribute__((ext_vector_type(4))) unsigned short u16x4;

static __device__ inline unsigned short f2b(float f) {
    __hip_bfloat16 h = __float2bfloat16(f);
    return *reinterpret_cast<unsigned short*>(&h);
}
static __device__ inline float b2f(unsigned short u) {
    unsigned int v = ((unsigned int)u) << 16;
    return __builtin_bit_cast(float, v);
}

// ---------------- Kernel P: zero-pad x (fp32, for kQV) ----------------
__global__ __launch_bounds__(256) void kP(const float* __restrict__ x,
                                          float* __restrict__ xpad) {
    int idx = blockIdx.x * 256 + threadIdx.x;
    if (idx >= XPAD_N) return;
    int c = idx % XPW;
    int t = idx / XPW;
    int r = t % XPH;
    t /= XPH;
    int rr = r - 3, cc = c - 3;
    float val = 0.0f;
    if (rr >= 0 && rr < HH && cc >= 0 && cc < WW)
        val = x[(size_t)t * (HH * WW) + rr * WW + cc];
    xpad[idx] = val;
}

// ---------------- Kernel X: dx-deinterleaved bf16 planes of x + ones ----
__global__ __launch_bounds__(256) void kX(const float* __restrict__ x,
                                          unsigned short* __restrict__ planes) {
    int idx = blockIdx.x * 256 + threadIdx.x;
    if (idx >= PLANES_N + ONES_N) return;
    if (idx >= PLANES_N) { planes[idx] = 0x3F80; return; }  // bf16 1.0
    int k = idx % QPW;
    int t = idx / QPW;
    int row = t % XPH; t /= XPH;
    int ci = t % IN_C; t /= IN_C;
    int dx = t % 7;
    int b  = t / 7;
    int r = row - 3;
    int c = 2 * k + dx - 3;
    float val = 0.0f;
    if (r >= 0 && r < HH && c >= 0 && c < WW)
        val = x[((size_t)(b * IN_C + ci) * HH + r) * WW + c];
    planes[idx] = f2b(val);
}

// ---------------- Kernel QV: q conv (-> qpadS bf16 shift-copies) + v conv ----
__global__ __launch_bounds__(256) void kQV(const float* __restrict__ xpad,
                                           const float* __restrict__ Wq,
                                           const float* __restrict__ bq,
                                           const float* __restrict__ Wv,
                                           const float* __restrict__ bv,
                                           unsigned short* __restrict__ qpadS,
                                           float* __restrict__ vpad) {
    int blk = blockIdx.x;               // b*70 + pb*10 + grp
    int grp = blk % 10;
    int t2  = blk / 10;
    int pb  = t2 % 7;
    int b   = t2 / 7;
    int tid = threadIdx.x;

    __shared__ float wlds[4 * IN_C * KK * 8];
    __shared__ float bsh[4];

    if (tid < 84) {
        int cc = tid / 21, rest = tid % 21;
        int ch = 4 * grp + cc;
        const float* wsrc = (ch < 24) ? (Wq + (size_t)ch * 147)
                                      : (Wv + (size_t)(ch - 24) * 147);
        #pragma unroll
        for (int dx = 0; dx < 7; ++dx) wlds[tid * 8 + dx] = wsrc[rest * 7 + dx];
        wlds[tid * 8 + 7] = 0.0f;
    }
    if (tid < 4) {
        int ch = 4 * grp + tid;
        bsh[tid] = (ch < 24) ? bq[ch] : bv[ch - 24];
    }
    __syncthreads();

    int pos = pb * 256 + tid;
    if (pos >= 112 * 14) return;
    int y   = pos / 14;
    int seg = pos - y * 14;

    float kv[4][8];
    #pragma unroll
    for (int cc = 0; cc < 4; ++cc)
        #pragma unroll
        for (int j = 0; j < 8; ++j) kv[cc][j] = bsh[cc];

    const float* xb = xpad + (size_t)b * IN_C * XPH * XPW;
    for (int ci = 0; ci < IN_C; ++ci) {
        const float* xrowbase = xb + (size_t)ci * (XPH * XPW) + (2 * y) * XPW + 16 * seg;
        for (int dy = 0; dy < KK; ++dy) {
            float xr[24];
            const float* xrow = xrowbase + dy * XPW;
            #pragma unroll
            for (int m = 0; m < 6; ++m)
                *(float4*)(&xr[4 * m]) = ((const float4*)xrow)[m];
            #pragma unroll
            for (int cc = 0; cc < 4; ++cc) {
                const float* wbase = &wlds[((cc * IN_C + ci) * KK + dy) * 8];
                float w[8];
                *(float4*)(&w[0]) = ((const float4*)wbase)[0];
                *(float4*)(&w[4]) = ((const float4*)wbase)[1];
                #pragma unroll
                for (int dx = 0; dx < 7; ++dx)
                    #pragma unroll
                    for (int j = 0; j < 8; ++j)
                        kv[cc][j] = fmaf(w[dx], xr[dx + 2 * j], kv[cc][j]);
            }
        }
    }

    int row = y + 3, c0 = 8 * seg + 3;
    if (grp < 6) {
        #pragma unroll
        for (int cc = 0; cc < 4; ++cc) {
            int ch = 4 * grp + cc;
            int icq = ch >> 3, qc = ch & 7;
            unsigned short* base = qpadS + (size_t)(b * IN_C + icq) * QPADS_STRIDE
                                 + (size_t)qc * 4 * QPH * QPW;
            #pragma unroll
            for (int tw = 0; tw < 4; ++tw) {
                unsigned short* bp = base + (tw * QPH + row) * QPW;
                #pragma unroll
                for (int j = 0; j < 8; ++j) {
                    int k = c0 + j - 2 * tw;
                    if (k >= 0) bp[k] = f2b(kv[cc][j]);
                }
            }
        }
    } else {
        #pragma unroll
        for (int cc = 0; cc < 4; ++cc) {
            int vc = 4 * grp + cc - 24;
            float* op = vpad + (((size_t)(b * V_C + vc)) * QPH + row) * QPW + c0;
            #pragma unroll
            for (int j = 0; j < 8; ++j) op[j] = kv[cc][j];
        }
    }
}

// ---------------- Kernel C: MFMA GEMM, split-K partials, NO atomics ---------
// Block = (b, nh, yc): 448 blocks, 512 threads / 8 waves. Each block: full
// M = 384 (wave w owns tiles w*3..w*3+2), N-half = 80 cols (nh), 8 yo rows.
// B half-tile (80 n x 136 k bf16) staged per y-row into LDS with register
// double-buffering (prefetch ry+1 while computing ry). Ones rows (n>=147)
// are constants -> prefilled once. Epilogue: plain packed bf16x4 stores into
// Dpart[yc] (transposed [n][m] layout), summed later by kR.
__global__ __launch_bounds__(512, 2) void kC(const unsigned short* __restrict__ planes,
                                             const unsigned short* __restrict__ qpadS,
                                             unsigned short* __restrict__ Dpart) {
    int blk = blockIdx.x;
    int b   = blk & 15;
    int r2  = blk >> 4;
    int nh  = r2 & 1;          // N-half: cols [nh*80, nh*80+80)
    int yc  = r2 >> 1;         // K-split: yo in [yc*8, yc*8+8)
    int tid = threadIdx.x;
    int w = tid >> 6, lane = tid & 63;
    int tt = lane & 15, kq = lane >> 4;
    int th = tt >> 2, tw = tt & 3;

    __shared__ uint4 smem[80 * 17];   // B half-tile: 80 n-rows x 136 bf16

    int nreal = nh ? 67 : 80;         // rows with real data (global n < 147)

    // zero k-pad slots [14,17) for real rows; prefill constant ones rows (nh=1)
    if (tid < nreal * 3) {
        int nl = tid / 3, j2 = tid % 3;
        smem[nl * 17 + 14 + j2] = uint4{0, 0, 0, 0};
    } else if (nh == 1) {
        int t2 = tid - 201;           // nreal*3 = 201
        if (t2 < 13 * 17) {
            int nl = 67 + t2 / 17, ss = t2 % 17;
            uint4 v = (ss < 14) ? uint4{0x3F803F80u, 0x3F803F80u, 0x3F803F80u, 0x3F803F80u}
                                : uint4{0, 0, 0, 0};
            smem[nl * 17 + ss] = v;
        }
    }

    // staging descriptors: chunk c = tid + 512*i over nreal*14 chunks (16B each)
    int nch = nreal * 14;
    int soff[3];
    int sdst[3];
    bool sact[3];
    #pragma unroll
    for (int i = 0; i < 3; ++i) {
        int c = tid + 512 * i;
        sact[i] = (c < nch);
        int cc2 = sact[i] ? c : 0;
        int nl = cc2 / 14;
        int k0 = (cc2 % 14) * 8;
        int n = nh * 80 + nl;         // global n < 147 guaranteed
        int ci = n / 49;
        int rr = n % 49;
        int dy = rr / 7;
        int dx = rr % 7;
        soff[i] = (((b * 7 + dx) * IN_C + ci) * XPH + dy) * QPW + k0;
        sdst[i] = nl * 17 + (k0 >> 3);
    }

    // A base pointers for this wave's 3 (ic,qc) tiles
    const unsigned short* abase[3];
    #pragma unroll
    for (int j = 0; j < 3; ++j) {
        int tile = w * 3 + j;
        int ic = tile >> 3, qc = tile & 7;
        abase[j] = qpadS + (size_t)(b * IN_C + ic) * QPADS_STRIDE
                 + ((qc * 4 + tw) * QPH + 2 * th) * QPW;
    }

    f32x4 acc[3][5];
    #pragma unroll
    for (int j = 0; j < 3; ++j)
        #pragma unroll
        for (int nt = 0; nt < 5; ++nt)
            acc[j][nt] = f32x4{0.f, 0.f, 0.f, 0.f};

    // prefetch B rows for ry=0
    uint4 pf[3];
    int yo0 = yc * 8;
    #pragma unroll
    for (int i = 0; i < 3; ++i)
        if (sact[i]) pf[i] = *(const uint4*)(planes + soff[i] + yo0 * 240);

    for (int ry = 0; ry < 8; ++ry) {
        int yo = yc * 8 + ry;
        __syncthreads();                       // prev compute done reading LDS
        #pragma unroll
        for (int i = 0; i < 3; ++i)
            if (sact[i]) smem[sdst[i]] = pf[i];
        __syncthreads();
        if (ry < 7) {                          // prefetch next row under compute
            #pragma unroll
            for (int i = 0; i < 3; ++i)
                if (sact[i]) pf[i] = *(const uint4*)(planes + soff[i] + (yo + 1) * 240);
        }
        #pragma unroll
        for (int s = 0; s < 4; ++s) {
            int k = 32 * s + kq * 8;
            int xs = (k < 112) ? k : 96;       // clamped; multiplies B-zeros
            bf16x8 af[3];
            #pragma unroll
            for (int j = 0; j < 3; ++j)
                af[j] = __builtin_bit_cast(bf16x8,
                    *(const uint4*)(abase[j] + yo * QPW + xs));
            #pragma unroll
            for (int nt = 0; nt < 5; ++nt) {
                bf16x8 bf = __builtin_bit_cast(bf16x8, smem[(nt * 16 + tt) * 17 + 4 * s + kq]);
                #pragma unroll
                for (int j = 0; j < 3; ++j)
                    acc[j][nt] = __builtin_amdgcn_mfma_f32_16x16x32_bf16(af[j], bf, acc[j][nt], 0, 0, 0);
            }
        }
    }

    // epilogue: plain packed stores to Dpart[yc][b][ic][n=160][m=128] (bf16).
    // C/D layout: col(n) = lane&15, row(m) = (lane>>4)*4+reg -> 4 consecutive
    // m per lane = one 8B store.
    #pragma unroll
    for (int j = 0; j < 3; ++j) {
        int tile = w * 3 + j;
        int ic = tile >> 3, qc = tile & 7;
        unsigned short* Dbi = Dpart + (size_t)((yc * 16 + b) * 3 + ic) * (160 * 128);
        int m = qc * 16 + kq * 4;
        #pragma unroll
        for (int nt = 0; nt < 5; ++nt) {
            int n = nh * 80 + nt * 16 + tt;
            u16x4 pk;
            pk.x = f2b(acc[j][nt][0]);
            pk.y = f2b(acc[j][nt][1]);
            pk.z = f2b(acc[j][nt][2]);
            pk.w = f2b(acc[j][nt][3]);
            *(u16x4*)(Dbi + (size_t)n * 128 + m) = pk;
        }
    }
}

// ---------------- Kernel R: reduce 14 bf16 split-K partials -> f32 D --------
__global__ __launch_bounds__(256) void kR(const unsigned short* __restrict__ Dpart,
                                          float* __restrict__ Df) {
    int idx = blockIdx.x * 256 + threadIdx.x;   // quad index
    if (idx >= D_N / 4) return;
    float4 s = float4{0.f, 0.f, 0.f, 0.f};
    #pragma unroll
    for (int yc = 0; yc < SPLITS; ++yc) {
        u16x4 v = *(const u16x4*)(Dpart + (size_t)yc * D_N + 4 * (size_t)idx);
        s.x += b2f(v.x);
        s.y += b2f(v.y);
        s.z += b2f(v.z);
        s.w += b2f(v.w);
    }
    *(float4*)(Df + 4 * (size_t)idx) = s;
}

// ---------------- Kernel E: a[v,t] = sum_{qc,r} Wk*D + sum_qc bk*D[147,.] ----
// D layout transposed: Df[bi][n=160][m=128], m = qc*16 + t. Thread (rl,t):
// t = tid&15 (coalesced along m), rl = tid>>4 owns r = rl+16j; LDS tree reduce.
__global__ __launch_bounds__(256) void kE(const float* __restrict__ Df,
                                          const float* __restrict__ Wk,
                                          const float* __restrict__ bk,
                                          float* __restrict__ a_out) {
    int blk = blockIdx.x;              // (b*3+ic)*16 + v
    int bi = blk >> 4;
    int v  = blk & 15;
    int ic = bi % IN_C;
    int tid = threadIdx.x;
    int t  = tid & 15;
    int rl = tid >> 4;
    const float* Dbase = Df + (size_t)bi * (160 * 128);
    const float* WkI = Wk + (size_t)(ic * V_C + v) * (Q_C * 147);
    const float* bkI = bk + (ic * V_C + v) * Q_C;
    float s = 0.0f;
    for (int qc = 0; qc < Q_C; ++qc) {
        const float* wrow = WkI + qc * 147;
        int mcol = qc * 16 + t;
        #pragma unroll
        for (int j = 0; j < 10; ++j) {
            int r = rl + 16 * j;
            if (r < 148) {
                float wv = (r < 147) ? wrow[r] : bkI[qc];   // col 147 = ones col
                s = fmaf(wv, Dbase[(size_t)r * 128 + mcol], s);
            }
        }
    }
    __shared__ float red[256];
    red[tid] = s;
    __syncthreads();
    if (tid < 16) {
        float acc2 = 0.f;
        #pragma unroll
        for (int k2 = 0; k2 < 16; ++k2) acc2 += red[k2 * 16 + tid];
        a_out[(size_t)blk * 16 + tid] = acc2;
    }
}

// ---------------- Kernel O: final dynamic conv -> out ----------------
__global__ __launch_bounds__(256) void kO(const float* __restrict__ vpad,
                                          const float* __restrict__ a,
                                          float* __restrict__ out) {
    int idx = blockIdx.x * 256 + threadIdx.x;
    if (idx >= OUT_N) return;
    int ow = idx % 58;
    int t = idx / 58;
    int oh = t % 58; t /= 58;
    int ic = t % IN_C;
    int b  = t / IN_C;
    const float* ab = a + (size_t)(b * IN_C + ic) * (V_C * 16);
    float s = 0.0f;
    for (int vc = 0; vc < V_C; ++vc) {
        const float* vrow = vpad + ((size_t)(b * V_C + vc) * QPH + 2 * oh) * QPW + 2 * ow;
        const float* ar = ab + vc * 16;
        #pragma unroll
        for (int kh = 0; kh < 4; ++kh)
            #pragma unroll
            for (int kw = 0; kw < 4; ++kw)
                s = fmaf(vrow[kh * QPW + kw], ar[kh * 4 + kw], s);
    }
    out[idx] = s;
}

extern "C" void kernel_launch(void* const* d_in, const int* in_sizes, int n_in,
                              void* d_out, int out_size, void* d_ws, size_t ws_size,
                              hipStream_t stream) {
    (void)in_sizes; (void)n_in; (void)out_size; (void)ws_size;
    const float* x  = (const float*)d_in[0];
    const float* Wq = (const float*)d_in[1];
    const float* bq = (const float*)d_in[2];
    const float* Wk = (const float*)d_in[3];
    const float* bk = (const float*)d_in[4];
    const float* Wv = (const float*)d_in[5];
    const float* bv = (const float*)d_in[6];
    float* out = (float*)d_out;

    char* p = (char*)d_ws;
    // Dpart (27.5 MiB) aliases xpad (10.25 MiB): xpad is dead before kC runs.
    unsigned short* Dpart = (unsigned short*)p;
    float*          xpad  = (float*)p;                  p += (size_t)DPART_N * 2;
    unsigned short* planes = (unsigned short*)p;        p += (size_t)(PLANES_N + ONES_N) * 2;
    float*          vpad   = (float*)p;                 p += (size_t)VPAD_N * 4;
    unsigned short* qpadS  = (unsigned short*)p;        p += (size_t)QPADS_N * 2;
    float*          Df     = (float*)p;                 p += (size_t)D_N * 4;
    float*          a      = (float*)p;
    // total ~103.1 MiB

    kP<<<(XPAD_N + 255) / 256, 256, 0, stream>>>(x, xpad);
    kX<<<(PLANES_N + ONES_N + 255) / 256, 256, 0, stream>>>(x, planes);
    // zero vpad borders + qpadS borders (contiguous). Dpart/Df fully written.
    hipMemsetAsync(vpad, 0, (size_t)VPAD_N * 4 + (size_t)QPADS_N * 2, stream);
    kQV<<<BATCH * 7 * 10, 256, 0, stream>>>(xpad, Wq, bq, Wv, bv, qpadS, vpad);
    kC<<<SPLITS * 2 * 16, 512, 0, stream>>>(planes, qpadS, Dpart);
    kR<<<(D_N / 4 + 255) / 256, 256, 0, stream>>>(Dpart, Df);
    kE<<<BATCH * IN_C * V_C, 256, 0, stream>>>(Df, Wk, bk, a);
    kO<<<(OUT_N + 255) / 256, 256, 0, stream>>>(vpad, a, out);
}

// Round 2
// 224.798 us; speedup vs baseline: 1.2386x; 1.2205x over previous
//
#include <hip/hip_runtime.h>
#include <hip/hip_bf16.h>

// Problem constants
#define BATCH 16
#define IN_C 3
#define Q_C 8
#define V_C 16
#define HH 224
#define WW 224
#define KK 7

// Padded layouts
#define XPH 230   // stored row = orig row + 3
#define XPW 232   // stored col = orig col + 3
#define QPH 118
#define QPW 120
#define QP_PLANE (QPH*QPW)            // 14160 per (qc)
#define QP_QSTRIDE (Q_C*QP_PLANE)     // 113280 per (b,ic)

// Region sizes (elements)
#define XPAD_N   (BATCH*IN_C*XPH*XPW)          // 2,561,280 f32
#define PLANES_N (BATCH*7*IN_C*XPH*QPW)        // 9,273,600 bf16
#define ONES_N   27712                          // bf16 ones (unused by kC now; kept)
#define VPAD_N   (BATCH*V_C*QPH*QPW)           // 3,624,960 f32
#define QPADS_N  (BATCH*IN_C*QP_QSTRIDE)       // 5,437,440 bf16 (single copy)
#define D_N      (BATCH*160*384)               // 983,040 elements [b][n=160][m'=384]
#define SPLITS   16
#define DPART_N  (SPLITS*D_N)                  // bf16 partials, 31.5 MB
#define A_N      (BATCH*IN_C*V_C*16)
#define OUT_N    (BATCH*IN_C*58*58)

typedef __attribute__((ext_vector_type(8))) short bf16x8;
typedef __attribute__((ext_vector_type(4))) float f32x4;
typedef __attribute__((ext_vector_type(4))) unsigned short u16x4;

// 4-byte-aligned 16B load (A-fragments are 4B-aligned: 2*tw bf16 shift = 4B)
struct __attribute__((packed, aligned(4))) uint4_a4 { uint4 v; };

static __device__ inline unsigned short f2b(float f) {
    __hip_bfloat16 h = __float2bfloat16(f);
    return *reinterpret_cast<unsigned short*>(&h);
}
static __device__ inline float b2f(unsigned short u) {
    unsigned int v = ((unsigned int)u) << 16;
    return __builtin_bit_cast(float, v);
}

// ---------------- Kernel P: zero-pad x (fp32, for kQV) ----------------
__global__ __launch_bounds__(256) void kP(const float* __restrict__ x,
                                          float* __restrict__ xpad) {
    int idx = blockIdx.x * 256 + threadIdx.x;
    if (idx >= XPAD_N) return;
    int c = idx % XPW;
    int t = idx / XPW;
    int r = t % XPH;
    t /= XPH;
    int rr = r - 3, cc = c - 3;
    float val = 0.0f;
    if (rr >= 0 && rr < HH && cc >= 0 && cc < WW)
        val = x[(size_t)t * (HH * WW) + rr * WW + cc];
    xpad[idx] = val;
}

// ---------------- Kernel X: dx-deinterleaved bf16 planes of x + ones ----
__global__ __launch_bounds__(256) void kX(const float* __restrict__ x,
                                          unsigned short* __restrict__ planes) {
    int idx = blockIdx.x * 256 + threadIdx.x;
    if (idx >= PLANES_N + ONES_N) return;
    if (idx >= PLANES_N) { planes[idx] = 0x3F80; return; }  // bf16 1.0
    int k = idx % QPW;
    int t = idx / QPW;
    int row = t % XPH; t /= XPH;
    int ci = t % IN_C; t /= IN_C;
    int dx = t % 7;
    int b  = t / 7;
    int r = row - 3;
    int c = 2 * k + dx - 3;
    float val = 0.0f;
    if (r >= 0 && r < HH && c >= 0 && c < WW)
        val = x[((size_t)(b * IN_C + ci) * HH + r) * WW + c];
    planes[idx] = f2b(val);
}

// ---------------- Kernel QV: q conv (single-copy bf16 q) + v conv ----
// Grid: 1120 blocks, swizzled so the 10 channel-groups sharing (b,pb) xpad
// data land on ONE XCD (same blk%8). Each thread computes 8 outputs for
// aligned store cols [8seg, 8seg+8), zero-masking pad cols -> one uint4
// store per q-channel, two float4 stores per v-channel.
__global__ __launch_bounds__(256) void kQV(const float* __restrict__ xpad,
                                           const float* __restrict__ Wq,
                                           const float* __restrict__ bq,
                                           const float* __restrict__ Wv,
                                           const float* __restrict__ bv,
                                           unsigned short* __restrict__ qpadS,
                                           float* __restrict__ vpad) {
    int blk = blockIdx.x;
    // de-swizzle: blk = ((q2*10)+g)*8 + r  ->  s = q2*8+r, grp = g
    int grp = (blk >> 3) % 10;
    int s   = (blk / 80) * 8 + (blk & 7);   // s in [0,112)
    int pb  = s % 7;
    int b   = s / 7;
    int tid = threadIdx.x;

    __shared__ float wlds[4 * IN_C * KK * 8];
    __shared__ float bsh[4];

    if (tid < 84) {
        int cc = tid / 21, rest = tid % 21;
        int ch = 4 * grp + cc;
        const float* wsrc = (ch < 24) ? (Wq + (size_t)ch * 147)
                                      : (Wv + (size_t)(ch - 24) * 147);
        #pragma unroll
        for (int dx = 0; dx < 7; ++dx) wlds[tid * 8 + dx] = wsrc[rest * 7 + dx];
        wlds[tid * 8 + 7] = 0.0f;
    }
    if (tid < 4) {
        int ch = 4 * grp + tid;
        bsh[tid] = (ch < 24) ? bq[ch] : bv[ch - 24];
    }
    __syncthreads();

    int pos = pb * 256 + tid;
    if (pos >= 112 * 15) return;
    int y   = pos / 15;
    int seg = pos - y * 15;                 // store cols [8seg, 8seg+8)

    float kv[4][8];
    #pragma unroll
    for (int cc = 0; cc < 4; ++cc)
        #pragma unroll
        for (int j = 0; j < 8; ++j) kv[cc][j] = bsh[cc];

    // output j: conv index k = 8seg-3+j; x padded cols 2k+dx = 16seg-6+2j+dx
    // xr window starts at col 16seg-8 (16B aligned; xpad has a 32B guard
    // before it so seg=0's pre-buffer bytes are safe garbage, masked below)
    const float* xb = xpad + (size_t)b * IN_C * XPH * XPW;
    for (int ci = 0; ci < IN_C; ++ci) {
        const float* xrowbase = xb + (size_t)ci * (XPH * XPW) + (2 * y) * XPW + 16 * seg - 8;
        for (int dy = 0; dy < KK; ++dy) {
            float xr[24];
            const float* xrow = xrowbase + dy * XPW;
            #pragma unroll
            for (int m = 0; m < 6; ++m)
                *(float4*)(&xr[4 * m]) = ((const float4*)xrow)[m];
            #pragma unroll
            for (int cc = 0; cc < 4; ++cc) {
                const float* wbase = &wlds[((cc * IN_C + ci) * KK + dy) * 8];
                float w[8];
                *(float4*)(&w[0]) = ((const float4*)wbase)[0];
                *(float4*)(&w[4]) = ((const float4*)wbase)[1];
                #pragma unroll
                for (int dx = 0; dx < 7; ++dx)
                    #pragma unroll
                    for (int j = 0; j < 8; ++j)
                        kv[cc][j] = fmaf(w[dx], xr[2 * j + dx + 2], kv[cc][j]);
            }
        }
    }

    int row = y + 3;
    int kbase = 8 * seg - 3;
    if (grp < 6) {
        #pragma unroll
        for (int cc = 0; cc < 4; ++cc) {
            int ch = 4 * grp + cc;
            int icq = ch >> 3, qc = ch & 7;
            unsigned short pk[8];
            #pragma unroll
            for (int j = 0; j < 8; ++j) {
                int k = kbase + j;
                pk[j] = (k >= 0 && k < 112) ? f2b(kv[cc][j]) : (unsigned short)0;
            }
            unsigned short* dst = qpadS + (size_t)((b * IN_C + icq) * Q_C + qc) * QP_PLANE
                                + row * QPW + 8 * seg;
            *(uint4*)dst = *(const uint4*)pk;
        }
    } else {
        #pragma unroll
        for (int cc = 0; cc < 4; ++cc) {
            int vc = 4 * grp + cc - 24;
            float f[8];
            #pragma unroll
            for (int j = 0; j < 8; ++j) {
                int k = kbase + j;
                f[j] = (k >= 0 && k < 112) ? kv[cc][j] : 0.0f;
            }
            float* op = vpad + ((size_t)(b * V_C + vc) * QPH + row) * QPW + 8 * seg;
            *(float4*)op = *(const float4*)f;
            *(float4*)(op + 4) = *(const float4*)(&f[4]);
        }
    }
}

// ---------------- Kernel C: MFMA GEMM, split-K partials, no atomics ---------
// Block = (b, nh, yc): 512 blocks (= exactly 2/CU), 512 threads / 8 waves.
// A read from single-copy qpadS at 4B-aligned addresses (2*tw shift).
// Epilogue: acc -> LDS transpose -> fully-coalesced 16B streaming stores
// into Dpart[yc][b][n=160][m'=384] bf16.
__global__ __launch_bounds__(512, 4) void kC(const unsigned short* __restrict__ planes,
                                             const unsigned short* __restrict__ qpadS,
                                             unsigned short* __restrict__ Dpart) {
    int blk = blockIdx.x;
    int b   = blk & 15;
    int nh  = (blk >> 4) & 1;      // N-half: cols [nh*80, nh*80+80)
    int yc  = blk >> 5;            // K-split: yo in [yc*7, yc*7+7)
    int tid = threadIdx.x;
    int w = tid >> 6, lane = tid & 63;
    int tt = lane & 15, kq = lane >> 4;
    int th = tt >> 2, tw = tt & 3;

    __shared__ union {
        uint4 bs[80 * 17];               // B half-tile: 80 n-rows x 136 bf16
        unsigned short dq[80 * 392];     // epilogue transpose: [n][m'=384]+pad
    } sm;

    int nreal = nh ? 67 : 80;            // rows with real data (global n < 147)

    // zero k-pad slots [14,17) for real rows; prefill constant ones rows (nh=1)
    if (tid < nreal * 3) {
        int nl = tid / 3, j2 = tid % 3;
        sm.bs[nl * 17 + 14 + j2] = uint4{0, 0, 0, 0};
    } else if (nh == 1) {
        int t2 = tid - nreal * 3;        // nreal*3 = 201
        if (t2 < 13 * 17) {
            int nl = 67 + t2 / 17, ss = t2 % 17;
            uint4 v = (ss < 14) ? uint4{0x3F803F80u, 0x3F803F80u, 0x3F803F80u, 0x3F803F80u}
                                : uint4{0, 0, 0, 0};
            sm.bs[nl * 17 + ss] = v;
        }
    }

    // staging descriptors: chunk c = tid + 512*i over nreal*14 chunks (16B each)
    int nch = nreal * 14;
    int soff[3];
    int sdst[3];
    bool sact[3];
    #pragma unroll
    for (int i = 0; i < 3; ++i) {
        int c = tid + 512 * i;
        sact[i] = (c < nch);
        int cc2 = sact[i] ? c : 0;
        int nl = cc2 / 14;
        int k0 = (cc2 % 14) * 8;
        int n = nh * 80 + nl;            // global n < 147 guaranteed
        int ci = n / 49;
        int rr = n % 49;
        int dy = rr / 7;
        int dx = rr % 7;
        soff[i] = (((b * 7 + dx) * IN_C + ci) * XPH + dy) * QPW + k0;
        sdst[i] = nl * 17 + (k0 >> 3);
    }

    // A base pointers: single-copy layout, column shift 2*tw (4B aligned)
    const unsigned short* abase[3];
    #pragma unroll
    for (int j = 0; j < 3; ++j) {
        int tile = w * 3 + j;
        int ic = tile >> 3, qc = tile & 7;
        abase[j] = qpadS + (size_t)(b * IN_C + ic) * QP_QSTRIDE + qc * QP_PLANE
                 + (2 * th) * QPW + 2 * tw;
    }

    f32x4 acc[3][5];
    #pragma unroll
    for (int j = 0; j < 3; ++j)
        #pragma unroll
        for (int nt = 0; nt < 5; ++nt)
            acc[j][nt] = f32x4{0.f, 0.f, 0.f, 0.f};

    // prefetch B rows for ry=0
    uint4 pf[3];
    int yo0 = yc * 7;
    #pragma unroll
    for (int i = 0; i < 3; ++i)
        if (sact[i]) pf[i] = *(const uint4*)(planes + soff[i] + yo0 * 240);

    for (int ry = 0; ry < 7; ++ry) {
        int yo = yc * 7 + ry;
        __syncthreads();                       // prev compute done reading LDS
        #pragma unroll
        for (int i = 0; i < 3; ++i)
            if (sact[i]) sm.bs[sdst[i]] = pf[i];
        __syncthreads();
        if (ry < 6) {                          // prefetch next row under compute
            #pragma unroll
            for (int i = 0; i < 3; ++i)
                if (sact[i]) pf[i] = *(const uint4*)(planes + soff[i] + (yo + 1) * 240);
        }
        #pragma unroll
        for (int s = 0; s < 4; ++s) {
            int k = 32 * s + kq * 8;
            int xs = (k < 112) ? k : 96;       // clamped; multiplies B-zeros
            bf16x8 af[3];
            #pragma unroll
            for (int j = 0; j < 3; ++j)
                af[j] = __builtin_bit_cast(bf16x8,
                    ((const uint4_a4*)(abase[j] + yo * QPW + xs))->v);
            #pragma unroll
            for (int nt = 0; nt < 5; ++nt) {
                bf16x8 bf = __builtin_bit_cast(bf16x8, sm.bs[(nt * 16 + tt) * 17 + 4 * s + kq]);
                #pragma unroll
                for (int j = 0; j < 3; ++j)
                    acc[j][nt] = __builtin_amdgcn_mfma_f32_16x16x32_bf16(af[j], bf, acc[j][nt], 0, 0, 0);
            }
        }
    }

    // ---- epilogue: LDS transpose -> coalesced streaming stores ----
    __syncthreads();                           // done reading sm.bs
    #pragma unroll
    for (int j = 0; j < 3; ++j) {
        int tile = w * 3 + j;
        int mb = tile * 16 + kq * 4;           // m' = ic*128 + qc*16 + kq*4
        #pragma unroll
        for (int nt = 0; nt < 5; ++nt) {
            int nl = nt * 16 + tt;
            u16x4 pk;
            pk.x = f2b(acc[j][nt][0]);
            pk.y = f2b(acc[j][nt][1]);
            pk.z = f2b(acc[j][nt][2]);
            pk.w = f2b(acc[j][nt][3]);
            *(u16x4*)(&sm.dq[nl * 392 + mb]) = pk;
        }
    }
    __syncthreads();
    unsigned short* Dp = Dpart + (size_t)(yc * 16 + b) * (160 * 384);
    for (int c = tid; c < 80 * 48; c += 512) { // 16B chunks: 80 rows x 48
        int nl = c / 48, ms = c % 48;
        *(uint4*)(Dp + (size_t)(nh * 80 + nl) * 384 + ms * 8) =
            *(const uint4*)(&sm.dq[nl * 392 + ms * 8]);
    }
}

// ---------------- Kernel R: reduce 16 bf16 split-K partials -> f32 D --------
__global__ __launch_bounds__(256) void kR(const unsigned short* __restrict__ Dpart,
                                          float* __restrict__ Df) {
    int idx = blockIdx.x * 256 + threadIdx.x;   // quad index, exact grid
    float4 s = float4{0.f, 0.f, 0.f, 0.f};
    #pragma unroll
    for (int yc = 0; yc < SPLITS; ++yc) {
        u16x4 v = *(const u16x4*)(Dpart + (size_t)yc * D_N + 4 * (size_t)idx);
        s.x += b2f(v.x);
        s.y += b2f(v.y);
        s.z += b2f(v.z);
        s.w += b2f(v.w);
    }
    *(float4*)(Df + 4 * (size_t)idx) = s;
}

// ---------------- Kernel E: a[v,t] = sum_{qc,r} Wk*D + sum_qc bk*D[147,.] ----
// Df layout: [b][n=160][m'=384], m' = ic*128 + qc*16 + t.
__global__ __launch_bounds__(256) void kE(const float* __restrict__ Df,
                                          const float* __restrict__ Wk,
                                          const float* __restrict__ bk,
                                          float* __restrict__ a_out) {
    int blk = blockIdx.x;              // (b*3+ic)*16 + v
    int bi = blk >> 4;
    int v  = blk & 15;
    int ic = bi % IN_C;
    int b  = bi / IN_C;
    int tid = threadIdx.x;
    int t  = tid & 15;
    int rl = tid >> 4;
    const float* Dbase = Df + (size_t)b * (160 * 384);
    const float* WkI = Wk + (size_t)(ic * V_C + v) * (Q_C * 147);
    const float* bkI = bk + (ic * V_C + v) * Q_C;
    float s = 0.0f;
    for (int qc = 0; qc < Q_C; ++qc) {
        const float* wrow = WkI + qc * 147;
        int mcol = ic * 128 + qc * 16 + t;
        #pragma unroll
        for (int j = 0; j < 10; ++j) {
            int r = rl + 16 * j;
            if (r < 148) {
                float wv = (r < 147) ? wrow[r] : bkI[qc];   // row 147 = ones row
                s = fmaf(wv, Dbase[(size_t)r * 384 + mcol], s);
            }
        }
    }
    __shared__ float red[256];
    red[tid] = s;
    __syncthreads();
    if (tid < 16) {
        float acc2 = 0.f;
        #pragma unroll
        for (int k2 = 0; k2 < 16; ++k2) acc2 += red[k2 * 16 + tid];
        a_out[(size_t)blk * 16 + tid] = acc2;
    }
}

// ---------------- Kernel O: final dynamic conv -> out ----------------
__global__ __launch_bounds__(256) void kO(const float* __restrict__ vpad,
                                          const float* __restrict__ a,
                                          float* __restrict__ out) {
    int idx = blockIdx.x * 256 + threadIdx.x;
    if (idx >= OUT_N) return;
    int ow = idx % 58;
    int t = idx / 58;
    int oh = t % 58; t /= 58;
    int ic = t % IN_C;
    int b  = t / IN_C;
    const float* ab = a + (size_t)(b * IN_C + ic) * (V_C * 16);
    float s = 0.0f;
    for (int vc = 0; vc < V_C; ++vc) {
        const float* vrow = vpad + ((size_t)(b * V_C + vc) * QPH + 2 * oh) * QPW + 2 * ow;
        const float* ar = ab + vc * 16;
        #pragma unroll
        for (int kh = 0; kh < 4; ++kh)
            #pragma unroll
            for (int kw = 0; kw < 4; ++kw)
                s = fmaf(vrow[kh * QPW + kw], ar[kh * 4 + kw], s);
    }
    out[idx] = s;
}

extern "C" void kernel_launch(void* const* d_in, const int* in_sizes, int n_in,
                              void* d_out, int out_size, void* d_ws, size_t ws_size,
                              hipStream_t stream) {
    (void)in_sizes; (void)n_in; (void)out_size; (void)ws_size;
    const float* x  = (const float*)d_in[0];
    const float* Wq = (const float*)d_in[1];
    const float* bq = (const float*)d_in[2];
    const float* Wk = (const float*)d_in[3];
    const float* bk = (const float*)d_in[4];
    const float* Wv = (const float*)d_in[5];
    const float* bv = (const float*)d_in[6];
    float* out = (float*)d_out;

    char* p = (char*)d_ws;
    // Dpart (31.5 MiB) aliases xpad (10.25 MiB + 32B guard): xpad dead by kC.
    unsigned short* Dpart = (unsigned short*)p;
    float*          xpad  = (float*)(p + 32);           // 32B guard for seg=0 pre-reads
    p += (size_t)DPART_N * 2;
    unsigned short* planes = (unsigned short*)p;        p += (size_t)(PLANES_N + ONES_N) * 2;
    float*          vpad   = (float*)p;                 p += (size_t)VPAD_N * 4;
    unsigned short* qpadS  = (unsigned short*)p;        p += (size_t)QPADS_N * 2;
    float*          Df     = (float*)p;                 p += (size_t)D_N * 4;
    float*          a      = (float*)p;
    // total ~79.4 MiB

    kP<<<(XPAD_N + 255) / 256, 256, 0, stream>>>(x, xpad);
    kX<<<(PLANES_N + ONES_N + 255) / 256, 256, 0, stream>>>(x, planes);
    // zero vpad borders + qpadS borders (contiguous, 25.4 MB)
    hipMemsetAsync(vpad, 0, (size_t)VPAD_N * 4 + (size_t)QPADS_N * 2, stream);
    kQV<<<BATCH * 7 * 10, 256, 0, stream>>>(xpad, Wq, bq, Wv, bv, qpadS, vpad);
    kC<<<SPLITS * 2 * 16, 512, 0, stream>>>(planes, qpadS, Dpart);
    kR<<<D_N / 4 / 256, 256, 0, stream>>>(Dpart, Df);
    kE<<<BATCH * IN_C * V_C, 256, 0, stream>>>(Df, Wk, bk, a);
    kO<<<(OUT_N + 255) / 256, 256, 0, stream>>>(vpad, a, out);
}